// Round 1
// baseline (303.096 us; speedup 1.0000x reference)
//
#include <hip/hip_runtime.h>
#include <stdint.h>

#define B_ 4
#define T_ 2048
#define D_ 1024
#define H_ 32

typedef unsigned short u16;
typedef __attribute__((ext_vector_type(8))) short bf16x8;
typedef __attribute__((ext_vector_type(4))) float f32x4;

__device__ __forceinline__ u16 f2bf(float f) {
  union { float f; unsigned u; } c; c.f = f;
  unsigned r = 0x7fffu + ((c.u >> 16) & 1u);
  return (u16)((c.u + r) >> 16);
}
__device__ __forceinline__ float bf2f(u16 h) {
  union { unsigned u; float f; } c; c.u = ((unsigned)h) << 16;
  return c.f;
}

__device__ __forceinline__ void gload_lds16(const void* g, void* l) {
  __builtin_amdgcn_global_load_lds(
      (const __attribute__((address_space(1))) void*)g,
      (__attribute__((address_space(3))) void*)l, 16, 0, 0);
}

// ---------------- elementwise f32 -> bf16 cast ----------------
__global__ void cast_f32_to_bf16(const float* __restrict__ in, u16* __restrict__ out, int n4) {
  int idx = blockIdx.x * 256 + threadIdx.x;
  int stride = gridDim.x * 256;
  for (int i = idx; i < n4; i += stride) {
    float4 v = reinterpret_cast<const float4*>(in)[i];
    ushort4 o;
    o.x = f2bf(v.x); o.y = f2bf(v.y); o.z = f2bf(v.z); o.w = f2bf(v.w);
    reinterpret_cast<ushort4*>(out)[i] = o;
  }
}

// ---------------- transpose + cast: out[j][i] = in[i][j] ----------------
__global__ void transpose_cast(const float* __restrict__ in, u16* __restrict__ out, int n) {
  __shared__ float tile[32][33];
  int tx = threadIdx.x & 31, ty = threadIdx.x >> 5;  // 32x8
  int c0 = blockIdx.x * 32, r0 = blockIdx.y * 32;
#pragma unroll
  for (int r = 0; r < 32; r += 8)
    tile[ty + r][tx] = in[(size_t)(r0 + ty + r) * n + c0 + tx];
  __syncthreads();
#pragma unroll
  for (int r = 0; r < 32; r += 8)
    out[(size_t)(c0 + ty + r) * n + r0 + tx] = f2bf(tile[tx][ty + r]);
}

// ---------------- bias2[d] = sum_j bq[j] * Wk[j][d] ----------------
__global__ void bias2_kernel(const float* __restrict__ bq, const float* __restrict__ Wk,
                             float* __restrict__ out) {
  int col = blockIdx.x * 256 + threadIdx.x;
  float acc = 0.f;
  for (int j = 0; j < D_; ++j) acc += bq[j] * Wk[(size_t)j * D_ + col];
  out[col] = acc;
}

// ---------------- bf16 NT GEMM: C[i,j] = sum_k A[i,k]*Bw[j,k] (+bias[j]) (+x[i,j]) ----
// 128x128 tile, BK=32, 256 threads (4 waves, 2x2 of 64x64 each)
template<int OUT_BF16, int ADD_X>
__global__ __launch_bounds__(256, 2)
void gemm_bt(const u16* __restrict__ A, const u16* __restrict__ Bw,
             const float* __restrict__ bias, const float* __restrict__ xadd,
             void* __restrict__ Cv, int M, int N, int K) {
  __shared__ u16 lA[128 * 32];
  __shared__ u16 lB[128 * 32];
  const int tid = threadIdx.x;
  const int bm = blockIdx.x, bn = blockIdx.y;
  const int w = tid >> 6, lane = tid & 63;
  const int wr = w >> 1, wc = w & 1;
  const int lr = lane & 15;
  const int lk = (lane >> 4) << 3;

  f32x4 acc[4][4] = {};

  const int c0 = tid, c1 = tid + 256;
  const size_t aoff0 = (size_t)(bm * 128 + (c0 >> 2)) * K + ((c0 & 3) << 3);
  const size_t aoff1 = (size_t)(bm * 128 + (c1 >> 2)) * K + ((c1 & 3) << 3);
  const size_t boff0 = (size_t)(bn * 128 + (c0 >> 2)) * K + ((c0 & 3) << 3);
  const size_t boff1 = (size_t)(bn * 128 + (c1 >> 2)) * K + ((c1 & 3) << 3);
  u16* lA0 = lA + c0 * 8; u16* lA1 = lA + c1 * 8;
  u16* lB0 = lB + c0 * 8; u16* lB1 = lB + c1 * 8;

  for (int k0 = 0; k0 < K; k0 += 32) {
    gload_lds16(A + aoff0 + k0, lA0);
    gload_lds16(A + aoff1 + k0, lA1);
    gload_lds16(Bw + boff0 + k0, lB0);
    gload_lds16(Bw + boff1 + k0, lB1);
    __syncthreads();
    bf16x8 aF[4], bF[4];
#pragma unroll
    for (int m = 0; m < 4; ++m)
      aF[m] = *reinterpret_cast<const bf16x8*>(&lA[(wr * 64 + m * 16 + lr) * 32 + lk]);
#pragma unroll
    for (int n = 0; n < 4; ++n)
      bF[n] = *reinterpret_cast<const bf16x8*>(&lB[(wc * 64 + n * 16 + lr) * 32 + lk]);
#pragma unroll
    for (int m = 0; m < 4; ++m)
#pragma unroll
      for (int n = 0; n < 4; ++n)
        acc[m][n] = __builtin_amdgcn_mfma_f32_16x16x32_bf16(aF[m], bF[n], acc[m][n], 0, 0, 0);
    __syncthreads();
  }

#pragma unroll
  for (int m = 0; m < 4; ++m) {
    const int row = bm * 128 + wr * 64 + m * 16 + ((lane >> 4) << 2);
#pragma unroll
    for (int n = 0; n < 4; ++n) {
      const int col = bn * 128 + wc * 64 + n * 16 + lr;
      const float bb = bias ? bias[col] : 0.f;
#pragma unroll
      for (int r = 0; r < 4; ++r) {
        float v = acc[m][n][r] + bb;
        if (ADD_X) v += xadd[(size_t)(row + r) * N + col];
        if (OUT_BF16) ((u16*)Cv)[(size_t)(row + r) * N + col] = f2bf(v);
        else          ((float*)Cv)[(size_t)(row + r) * N + col] = v;
      }
    }
  }
}

// ---------------- attention over own-history slice ----------------
// block = one t; 4 waves = 4 batches; scores = Q2[b,t]·hist[t,h]/32 + log(decay[31-h]+1e-10)
// hw[b,t,:] = sum_h softmax(scores)[h] * hist[t,h,:]
__global__ __launch_bounds__(256, 2)
void attn_kernel(const u16* __restrict__ Q2, const float* __restrict__ hist,
                 const float* __restrict__ decay, u16* __restrict__ hw) {
  __shared__ u16 lh[H_ * D_];  // 64KB bf16 history tile
  const int t = blockIdx.x;
  const int tid = threadIdx.x;
  const float* hp = hist + (size_t)t * (H_ * D_);
  for (int c = tid; c < (H_ * D_) / 8; c += 256) {
    float4 f0 = reinterpret_cast<const float4*>(hp)[2 * c];
    float4 f1 = reinterpret_cast<const float4*>(hp)[2 * c + 1];
    bf16x8 o;
    o[0] = (short)f2bf(f0.x); o[1] = (short)f2bf(f0.y);
    o[2] = (short)f2bf(f0.z); o[3] = (short)f2bf(f0.w);
    o[4] = (short)f2bf(f1.x); o[5] = (short)f2bf(f1.y);
    o[6] = (short)f2bf(f1.z); o[7] = (short)f2bf(f1.w);
    reinterpret_cast<bf16x8*>(lh)[c] = o;
  }
  __syncthreads();

  const int b = tid >> 6, lane = tid & 63;
  const int d0 = lane * 16;
  const size_t row = (size_t)b * T_ + t;
  float q[16];
  {
    const bf16x8 qa = *reinterpret_cast<const bf16x8*>(Q2 + row * D_ + d0);
    const bf16x8 qb = *reinterpret_cast<const bf16x8*>(Q2 + row * D_ + d0 + 8);
#pragma unroll
    for (int j = 0; j < 8; ++j) { q[j] = bf2f((u16)qa[j]); q[8 + j] = bf2f((u16)qb[j]); }
  }
  float s[H_];
#pragma unroll 4
  for (int h = 0; h < H_; ++h) {
    const bf16x8 k0 = *reinterpret_cast<const bf16x8*>(&lh[h * D_ + d0]);
    const bf16x8 k1 = *reinterpret_cast<const bf16x8*>(&lh[h * D_ + d0 + 8]);
    float p = 0.f;
#pragma unroll
    for (int j = 0; j < 8; ++j) p += q[j] * bf2f((u16)k0[j]);
#pragma unroll
    for (int j = 0; j < 8; ++j) p += q[8 + j] * bf2f((u16)k1[j]);
#pragma unroll
    for (int m = 32; m >= 1; m >>= 1) p += __shfl_xor(p, m);
    s[h] = p;
  }
  float mx = -1e30f;
#pragma unroll
  for (int h = 0; h < H_; ++h) {
    const float bias = __logf(decay[H_ - 1 - h] + 1e-10f);
    s[h] = s[h] * 0.03125f + bias;
    mx = fmaxf(mx, s[h]);
  }
  float sum = 0.f;
#pragma unroll
  for (int h = 0; h < H_; ++h) { s[h] = __expf(s[h] - mx); sum += s[h]; }
  const float inv = 1.f / sum;
  float acc[16] = {};
#pragma unroll 4
  for (int h = 0; h < H_; ++h) {
    const float ph = s[h] * inv;
    const bf16x8 v0 = *reinterpret_cast<const bf16x8*>(&lh[h * D_ + d0]);
    const bf16x8 v1 = *reinterpret_cast<const bf16x8*>(&lh[h * D_ + d0 + 8]);
#pragma unroll
    for (int j = 0; j < 8; ++j) {
      acc[j] += ph * bf2f((u16)v0[j]);
      acc[8 + j] += ph * bf2f((u16)v1[j]);
    }
  }
  bf16x8 o0, o1;
#pragma unroll
  for (int j = 0; j < 8; ++j) { o0[j] = (short)f2bf(acc[j]); o1[j] = (short)f2bf(acc[8 + j]); }
  *reinterpret_cast<bf16x8*>(hw + row * D_ + d0) = o0;
  *reinterpret_cast<bf16x8*>(hw + row * D_ + d0 + 8) = o1;
}

extern "C" void kernel_launch(void* const* d_in, const int* in_sizes, int n_in,
                              void* d_out, int out_size, void* d_ws, size_t ws_size,
                              hipStream_t stream) {
  (void)in_sizes; (void)n_in; (void)out_size; (void)ws_size;
  const float* x     = (const float*)d_in[0];
  const float* hist  = (const float*)d_in[1];
  const float* Wq    = (const float*)d_in[2];
  const float* bq    = (const float*)d_in[3];
  const float* Wk    = (const float*)d_in[4];
  // d_in[5] = bk: exactly cancelled by softmax shift-invariance (constant over h)
  const float* Wv    = (const float*)d_in[6];
  const float* bv    = (const float*)d_in[7];
  const float* Wo    = (const float*)d_in[8];
  const float* bo    = (const float*)d_in[9];
  const float* decay = (const float*)d_in[10];

  char* p = (char*)d_ws;
  u16* wqtb = (u16*)p; p += (size_t)D_ * D_ * 2;   // Wq^T bf16
  u16* wktb = (u16*)p; p += (size_t)D_ * D_ * 2;   // Wk^T bf16
  u16* wvb  = (u16*)p; p += (size_t)D_ * D_ * 2;   // Wv bf16
  u16* wob  = (u16*)p; p += (size_t)D_ * D_ * 2;   // Wo bf16
  u16* wqk  = (u16*)p; p += (size_t)D_ * D_ * 2;   // (Wq^T Wk)^T bf16
  float* bias2 = (float*)p; p += 4096;             // bq @ Wk
  u16* xb   = (u16*)p; p += (size_t)B_ * T_ * D_ * 2;
  u16* Q2b  = (u16*)p; p += (size_t)B_ * T_ * D_ * 2;
  u16* hwb  = (u16*)p; p += (size_t)B_ * T_ * D_ * 2;
  u16* attb = (u16*)p; p += (size_t)B_ * T_ * D_ * 2;

  const int M = B_ * T_;  // 8192

  transpose_cast<<<dim3(32, 32), 256, 0, stream>>>(Wq, wqtb, D_);
  transpose_cast<<<dim3(32, 32), 256, 0, stream>>>(Wk, wktb, D_);
  cast_f32_to_bf16<<<1024, 256, 0, stream>>>(Wv, wvb, D_ * D_ / 4);
  cast_f32_to_bf16<<<1024, 256, 0, stream>>>(Wo, wob, D_ * D_ / 4);
  cast_f32_to_bf16<<<2048, 256, 0, stream>>>(x, xb, M * D_ / 4);
  bias2_kernel<<<D_ / 256, 256, 0, stream>>>(bq, Wk, bias2);

  // Wqk^T[d,a] = sum_j Wk[j,d]*Wq[j,a]
  gemm_bt<1, 0><<<dim3(D_ / 128, D_ / 128), 256, 0, stream>>>(
      wktb, wqtb, nullptr, nullptr, wqk, D_, D_, D_);
  // Q2[i,d] = sum_a x[i,a]*Wqk[a,d] + bias2[d]
  gemm_bt<1, 0><<<dim3(M / 128, D_ / 128), 256, 0, stream>>>(
      xb, wqk, bias2, nullptr, Q2b, M, D_, D_);
  // attention -> hw
  attn_kernel<<<T_, 256, 0, stream>>>(Q2b, hist, decay, hwb);
  // attb = hw @ Wv^T + bv + x
  gemm_bt<1, 1><<<dim3(M / 128, D_ / 128), 256, 0, stream>>>(
      hwb, wvb, bv, x, attb, M, D_, D_);
  // out = attb @ Wo^T + bo  (f32)
  gemm_bt<0, 0><<<dim3(M / 128, D_ / 128), 256, 0, stream>>>(
      attb, wob, bo, nullptr, (float*)d_out, M, D_, D_);
}